// Round 1
// baseline (2691.261 us; speedup 1.0000x reference)
//
#include <hip/hip_runtime.h>
#include <stdint.h>
#include <math.h>

#define T_STEPS 4096
#define BATCH   256

// LIF step with threshold = 1.0:
//   v' = alpha*v + xs          (xs already includes the (1-alpha) factor)
//   s  = max(floor(v'), 0)
//   v  = v' - s
// Identity: v_new = min(v', fract(v'));  s = v' - v_new   (exact in fp32)
__device__ __forceinline__ float lif_step(float& v, float xs, float alpha) {
    float vp = fmaf(alpha, v, xs);
    float fr = vp - floorf(vp);     // fract(v') — exact
    float vn = fminf(vp, fr);       // v'<0 -> v', v'>=0 -> fract(v')
    float s  = vp - vn;             // = max(floor(v'),0), exact
    v = vn;
    return s;
}

__device__ __forceinline__ float ub(uint32_t w, int k) {
    return (float)((w >> (k * 8)) & 0xffu);   // -> v_cvt_f32_ubyteK
}

// ---------------- Layer 1: fp32 data [B,T,16] -> u8 spikes [B,T,16] ----------
__global__ __launch_bounds__(64) void lif_l1(
    const float* __restrict__ data, const float* __restrict__ w1,
    uint8_t* __restrict__ s1, float alpha)
{
    const int lane = threadIdx.x;
    const int co   = lane & 15;
    const int b    = blockIdx.x * 4 + (lane >> 4);
    const float one_m = 1.0f - alpha;

    float wr[16];
#pragma unroll
    for (int i = 0; i < 16; ++i) wr[i] = one_m * w1[co * 16 + i];

    const float4* xp = (const float4*)(data + (size_t)b * T_STEPS * 16);
    uint8_t* op = s1 + (size_t)b * T_STEPS * 16 + co;

    float v = 0.0f;
    float4 n0 = xp[0], n1 = xp[1], n2 = xp[2], n3 = xp[3];
    for (int t = 0; t < T_STEPS; ++t) {
        float4 c0 = n0, c1 = n1, c2 = n2, c3 = n3;
        int tn = (t + 1 < T_STEPS) ? (t + 1) : t;
        n0 = xp[tn * 4 + 0]; n1 = xp[tn * 4 + 1];
        n2 = xp[tn * 4 + 2]; n3 = xp[tn * 4 + 3];

        // dot(w_row, x_row), 4 independent partial chains for ILP
        float p0 = fmaf(wr[1], c0.y, wr[0] * c0.x);
        p0 = fmaf(wr[2], c0.z, p0);  p0 = fmaf(wr[3], c0.w, p0);
        float p1 = fmaf(wr[5], c1.y, wr[4] * c1.x);
        p1 = fmaf(wr[6], c1.z, p1);  p1 = fmaf(wr[7], c1.w, p1);
        float p2 = fmaf(wr[9], c2.y, wr[8] * c2.x);
        p2 = fmaf(wr[10], c2.z, p2); p2 = fmaf(wr[11], c2.w, p2);
        float p3 = fmaf(wr[13], c3.y, wr[12] * c3.x);
        p3 = fmaf(wr[14], c3.z, p3); p3 = fmaf(wr[15], c3.w, p3);
        float xs = (p0 + p1) + (p2 + p3);

        float s = lif_step(v, xs, alpha);
        op[t * 16] = (uint8_t)(int)s;
    }
}

// ---------------- Layer 2: u8 spikes [B,T,16] -> u8 spikes [B,T,32] ----------
__global__ __launch_bounds__(64) void lif_l2(
    const uint8_t* __restrict__ s1, const float* __restrict__ w2,
    uint8_t* __restrict__ s2, float alpha)
{
    const int lane = threadIdx.x;
    const int co   = lane & 31;
    const int b    = blockIdx.x * 2 + (lane >> 5);
    const float one_m = 1.0f - alpha;

    float wr[16];
#pragma unroll
    for (int i = 0; i < 16; ++i) wr[i] = one_m * w2[co * 16 + i];

    const uint4* xp = (const uint4*)(s1 + (size_t)b * T_STEPS * 16);
    uint8_t* op = s2 + (size_t)b * T_STEPS * 32 + co;

    float v = 0.0f;
    uint4 n = xp[0];
    for (int t = 0; t < T_STEPS; ++t) {
        uint4 c = n;
        int tn = (t + 1 < T_STEPS) ? (t + 1) : t;
        n = xp[tn];

        float xs = 0.0f;
        if (c.x | c.y | c.z | c.w) {   // rare: any input spike this step
            float p0 = fmaf(wr[1], ub(c.x,1), wr[0] * ub(c.x,0));
            p0 = fmaf(wr[2], ub(c.x,2), p0);  p0 = fmaf(wr[3], ub(c.x,3), p0);
            float p1 = fmaf(wr[5], ub(c.y,1), wr[4] * ub(c.y,0));
            p1 = fmaf(wr[6], ub(c.y,2), p1);  p1 = fmaf(wr[7], ub(c.y,3), p1);
            float p2 = fmaf(wr[9], ub(c.z,1), wr[8] * ub(c.z,0));
            p2 = fmaf(wr[10], ub(c.z,2), p2); p2 = fmaf(wr[11], ub(c.z,3), p2);
            float p3 = fmaf(wr[13], ub(c.w,1), wr[12] * ub(c.w,0));
            p3 = fmaf(wr[14], ub(c.w,2), p3); p3 = fmaf(wr[15], ub(c.w,3), p3);
            xs = (p0 + p1) + (p2 + p3);
        }
        float s = lif_step(v, xs, alpha);
        op[t * 32] = (uint8_t)(int)s;
    }
}

// ---------------- Layer 3: u8 spikes [B,T,32] -> fp32 out [B,T,10] -----------
__global__ __launch_bounds__(64) void lif_l3(
    const uint8_t* __restrict__ s2, const float* __restrict__ w3,
    float* __restrict__ out, float alpha)
{
    const int lane = threadIdx.x;
    const int co   = lane & 15;          // 10 active, 6 idle
    const int b    = blockIdx.x * 4 + (lane >> 4);
    const float one_m = 1.0f - alpha;
    const bool active = (co < 10);

    float wr[32];
#pragma unroll
    for (int i = 0; i < 32; ++i) wr[i] = active ? (one_m * w3[co * 32 + i]) : 0.0f;

    const uint4* xp = (const uint4*)(s2 + (size_t)b * T_STEPS * 32); // 2 uint4 / row
    float* op = out + (size_t)b * T_STEPS * 10 + co;

    float v = 0.0f;
    uint4 na = xp[0], nb = xp[1];
    for (int t = 0; t < T_STEPS; ++t) {
        uint4 ca = na, cb = nb;
        int tn = (t + 1 < T_STEPS) ? (t + 1) : t;
        na = xp[tn * 2 + 0]; nb = xp[tn * 2 + 1];

        float xs = 0.0f;
        if (ca.x | ca.y | ca.z | ca.w | cb.x | cb.y | cb.z | cb.w) {
            float p0 = fmaf(wr[1], ub(ca.x,1), wr[0] * ub(ca.x,0));
            p0 = fmaf(wr[2],  ub(ca.x,2), p0); p0 = fmaf(wr[3],  ub(ca.x,3), p0);
            p0 = fmaf(wr[4],  ub(ca.y,0), p0); p0 = fmaf(wr[5],  ub(ca.y,1), p0);
            p0 = fmaf(wr[6],  ub(ca.y,2), p0); p0 = fmaf(wr[7],  ub(ca.y,3), p0);
            float p1 = fmaf(wr[9], ub(ca.z,1), wr[8] * ub(ca.z,0));
            p1 = fmaf(wr[10], ub(ca.z,2), p1); p1 = fmaf(wr[11], ub(ca.z,3), p1);
            p1 = fmaf(wr[12], ub(ca.w,0), p1); p1 = fmaf(wr[13], ub(ca.w,1), p1);
            p1 = fmaf(wr[14], ub(ca.w,2), p1); p1 = fmaf(wr[15], ub(ca.w,3), p1);
            float p2 = fmaf(wr[17], ub(cb.x,1), wr[16] * ub(cb.x,0));
            p2 = fmaf(wr[18], ub(cb.x,2), p2); p2 = fmaf(wr[19], ub(cb.x,3), p2);
            p2 = fmaf(wr[20], ub(cb.y,0), p2); p2 = fmaf(wr[21], ub(cb.y,1), p2);
            p2 = fmaf(wr[22], ub(cb.y,2), p2); p2 = fmaf(wr[23], ub(cb.y,3), p2);
            float p3 = fmaf(wr[25], ub(cb.z,1), wr[24] * ub(cb.z,0));
            p3 = fmaf(wr[26], ub(cb.z,2), p3); p3 = fmaf(wr[27], ub(cb.z,3), p3);
            p3 = fmaf(wr[28], ub(cb.w,0), p3); p3 = fmaf(wr[29], ub(cb.w,1), p3);
            p3 = fmaf(wr[30], ub(cb.w,2), p3); p3 = fmaf(wr[31], ub(cb.w,3), p3);
            xs = (p0 + p1) + (p2 + p3);
        }
        float s = lif_step(v, xs, alpha);
        if (active) op[t * 10] = s;
    }
}

extern "C" void kernel_launch(void* const* d_in, const int* in_sizes, int n_in,
                              void* d_out, int out_size, void* d_ws, size_t ws_size,
                              hipStream_t stream)
{
    const float* data = (const float*)d_in[0];
    const float* w1   = (const float*)d_in[1];
    const float* w2   = (const float*)d_in[2];
    const float* w3   = (const float*)d_in[3];
    float* out = (float*)d_out;

    uint8_t* s1 = (uint8_t*)d_ws;                                   // 16 MiB
    uint8_t* s2 = s1 + (size_t)BATCH * T_STEPS * 16;                // 32 MiB

    const float alpha = expf(-1.0f / 20.0f);

    lif_l1<<<BATCH / 4, 64, 0, stream>>>(data, w1, s1, alpha);
    lif_l2<<<BATCH / 2, 64, 0, stream>>>(s1, w2, s2, alpha);
    lif_l3<<<BATCH / 4, 64, 0, stream>>>(s2, w3, out, alpha);
}

// Round 2
// 409.031 us; speedup vs baseline: 6.5796x; 6.5796x over previous
//
#include <hip/hip_runtime.h>
#include <stdint.h>
#include <math.h>

#define T_STEPS 4096
#define BATCH   256
#define NB_BLK  256      // T/16 spike blocks per chain
#define CHUNK_B 128      // batch chunk for layer-1 GEMM staging

// LIF step, threshold=1:  v'=alpha*v+xs; s=max(floor(v'),0); v=v'-s
// Identity: v_new = min(v', fract(v')); s = v' - v_new (exact fp32).
// Invariant: after any step, v < 1.  => zero-input step is exactly v *= alpha
// (fmaf(a,v,+0) == a*v bit-exactly here) and can never spike.
__device__ __forceinline__ float lif_step(float& v, float xs, float alpha) {
    float vp = fmaf(alpha, v, xs);
    float fr = vp - floorf(vp);
    float vn = fminf(vp, fr);
    float s  = vp - vn;
    v = vn;
    return s;
}

__device__ __forceinline__ float ubf(uint32_t w, int k) {
    return (float)((w >> (k * 8)) & 0xffu);
}

// ---------------- zero-fill d_out + bitmaps ---------------------------------
__global__ __launch_bounds__(256) void kzero(float4* __restrict__ out4,
                                             float4* __restrict__ bm4,
                                             int nout4, int nbm4)
{
    int i = blockIdx.x * 256 + threadIdx.x;
    int stride = gridDim.x * 256;
    float4 z = make_float4(0.f, 0.f, 0.f, 0.f);
    for (int k = i; k < nout4; k += stride) out4[k] = z;
    for (int k = i; k < nbm4; k += stride) bm4[k] = z;
}

// ---------------- layer-1 GEMM: x[b,t,16] -> y[bi][co][t] (chunk, fp32) -----
// Arithmetic identical to round-1 fused kernel (verified absmax 0.0).
__global__ __launch_bounds__(256) void gemm1(const float* __restrict__ x,
        const float* __restrict__ w1, float* __restrict__ y,
        float one_m, int b0)
{
    const int tid = threadIdx.x;
    const int tl  = tid & 15;                 // t within 16-row group
    const int co  = tid >> 4;                 // 0..15 output channel
    const int bi  = blockIdx.x >> 6;          // chunk-local batch
    const int t0  = (blockIdx.x & 63) * 64;   // 64 t per block
    const int b   = b0 + bi;

    float wr[16];
#pragma unroll
    for (int i = 0; i < 16; ++i) wr[i] = one_m * w1[co * 16 + i];

    const float4* xp = (const float4*)(x + (size_t)b * T_STEPS * 16);
    float* yp = y + ((size_t)bi * 16 + co) * T_STEPS;

#pragma unroll
    for (int j = 0; j < 4; ++j) {
        int t = t0 + j * 16 + tl;
        float4 c0 = xp[t * 4 + 0], c1 = xp[t * 4 + 1];
        float4 c2 = xp[t * 4 + 2], c3 = xp[t * 4 + 3];
        float p0 = fmaf(wr[1], c0.y, wr[0] * c0.x);
        p0 = fmaf(wr[2], c0.z, p0);  p0 = fmaf(wr[3], c0.w, p0);
        float p1 = fmaf(wr[5], c1.y, wr[4] * c1.x);
        p1 = fmaf(wr[6], c1.z, p1);  p1 = fmaf(wr[7], c1.w, p1);
        float p2 = fmaf(wr[9], c2.y, wr[8] * c2.x);
        p2 = fmaf(wr[10], c2.z, p2); p2 = fmaf(wr[11], c2.w, p2);
        float p3 = fmaf(wr[13], c3.y, wr[12] * c3.x);
        p3 = fmaf(wr[14], c3.z, p3); p3 = fmaf(wr[15], c3.w, p3);
        yp[t] = (p0 + p1) + (p2 + p3);
    }
}

// ---------------- layer-1 scan: y stream -> s1t[b][c][t] u8 + bitmap --------
__global__ __launch_bounds__(64) void scan1(const float* __restrict__ y,
        uint8_t* __restrict__ s1t, uint8_t* __restrict__ bm1,
        float alpha, int b0)
{
    const int tid = threadIdx.x;
    const int co  = tid & 15;
    const int bi  = blockIdx.x * 4 + (tid >> 4);
    const int b   = b0 + bi;

    const float4* yp = (const float4*)(y + ((size_t)bi * 16 + co) * T_STEPS);
    uint4* op = (uint4*)(s1t + ((size_t)b * 16 + co) * T_STEPS);
    uint8_t* bmp = bm1 + (size_t)b * NB_BLK;

    float v = 0.0f;
    float4 A[4], Bq[4];
#pragma unroll
    for (int k = 0; k < 4; ++k) A[k] = yp[k];
#pragma unroll
    for (int k = 0; k < 4; ++k) Bq[k] = yp[4 + k];

    for (int tb = 0; tb < NB_BLK; ++tb) {
        float cf[16];
#pragma unroll
        for (int k = 0; k < 4; ++k) {
            cf[k * 4 + 0] = A[k].x; cf[k * 4 + 1] = A[k].y;
            cf[k * 4 + 2] = A[k].z; cf[k * 4 + 3] = A[k].w;
        }
#pragma unroll
        for (int k = 0; k < 4; ++k) A[k] = Bq[k];
        int tbn = (tb + 2 <= NB_BLK - 1) ? tb + 2 : NB_BLK - 1;
#pragma unroll
        for (int k = 0; k < 4; ++k) Bq[k] = yp[tbn * 4 + k];

        uint32_t w[4] = {0u, 0u, 0u, 0u};
#pragma unroll
        for (int j = 0; j < 16; ++j) {
            float s = lif_step(v, cf[j], alpha);
            w[j >> 2] |= ((uint32_t)(int)s) << ((j & 3) * 8);
        }
        op[tb] = make_uint4(w[0], w[1], w[2], w[3]);
        if (w[0] | w[1] | w[2] | w[3]) bmp[tb] = 1;
    }
}

// ---------------- layer-2: sparse scan, s1t -> s2t + bitmap2 ----------------
__global__ __launch_bounds__(64) void scan2(const uint8_t* __restrict__ s1t,
        const float* __restrict__ w2, uint8_t* __restrict__ s2t,
        const uint8_t* __restrict__ bm1, uint8_t* __restrict__ bm2,
        float alpha, float one_m)
{
    const int tid = threadIdx.x;
    const int co  = tid & 31;
    const int b   = blockIdx.x * 2 + (tid >> 5);

    float wr[16];
#pragma unroll
    for (int i = 0; i < 16; ++i) wr[i] = one_m * w2[co * 16 + i];

    const uint8_t* sbase = s1t + (size_t)b * 16 * T_STEPS;
    uint4* op = (uint4*)(s2t + ((size_t)b * 32 + co) * T_STEPS);
    const uint4* bmv = (const uint4*)(bm1 + (size_t)b * NB_BLK);
    uint8_t* bm2p = bm2 + (size_t)b * NB_BLK;

    float v = 0.0f;
    for (int sb = 0; sb < 16; ++sb) {
        uint4 bm = bmv[sb];
        if ((bm.x | bm.y | bm.z | bm.w) == 0u) {
            if (v != 0.0f) {
                for (int blk = 0; blk < 16 && v != 0.0f; ++blk) {
#pragma unroll
                    for (int j = 0; j < 16; ++j) v *= alpha;
                }
            }
            continue;
        }
        for (int blk = 0; blk < 16; ++blk) {
            uint32_t d = (blk < 4) ? bm.x : (blk < 8) ? bm.y
                       : (blk < 12) ? bm.z : bm.w;
            uint32_t byte = (d >> ((blk & 3) * 8)) & 0xffu;
            if (byte == 0u) {
                if (v != 0.0f) {
#pragma unroll
                    for (int j = 0; j < 16; ++j) v *= alpha;
                }
                continue;
            }
            const int tb = sb * 16 + blk;
            const int t0 = tb * 16;
            uint4 S[16];
#pragma unroll
            for (int c = 0; c < 16; ++c)
                S[c] = *(const uint4*)(sbase + (size_t)c * T_STEPS + t0);
            uint32_t w[4] = {0u, 0u, 0u, 0u};
#pragma unroll
            for (int j = 0; j < 16; ++j) {
                float xv[16];
#pragma unroll
                for (int c = 0; c < 16; ++c) {
                    uint32_t dd = (j < 4) ? S[c].x : (j < 8) ? S[c].y
                                : (j < 12) ? S[c].z : S[c].w;
                    xv[c] = ubf(dd, j & 3);
                }
                float p0 = fmaf(wr[1], xv[1], wr[0] * xv[0]);
                p0 = fmaf(wr[2], xv[2], p0);   p0 = fmaf(wr[3], xv[3], p0);
                float p1 = fmaf(wr[5], xv[5], wr[4] * xv[4]);
                p1 = fmaf(wr[6], xv[6], p1);   p1 = fmaf(wr[7], xv[7], p1);
                float p2 = fmaf(wr[9], xv[9], wr[8] * xv[8]);
                p2 = fmaf(wr[10], xv[10], p2); p2 = fmaf(wr[11], xv[11], p2);
                float p3 = fmaf(wr[13], xv[13], wr[12] * xv[12]);
                p3 = fmaf(wr[14], xv[14], p3); p3 = fmaf(wr[15], xv[15], p3);
                float xs = (p0 + p1) + (p2 + p3);
                float s = lif_step(v, xs, alpha);
                w[j >> 2] |= ((uint32_t)(int)s) << ((j & 3) * 8);
            }
            op[tb] = make_uint4(w[0], w[1], w[2], w[3]);
            if (w[0] | w[1] | w[2] | w[3]) bm2p[tb] = 1;
        }
    }
}

// ---------------- layer-3: sparse scan, s2t -> out[b,t,10] (pre-zeroed) -----
__global__ __launch_bounds__(64) void scan3(const uint8_t* __restrict__ s2t,
        const float* __restrict__ w3, float* __restrict__ out,
        const uint8_t* __restrict__ bm2, float alpha, float one_m)
{
    const int tid = threadIdx.x;
    const int co  = tid & 15;           // 10 active
    const int b   = blockIdx.x * 4 + (tid >> 4);
    const bool active = (co < 10);

    float wr[32];
#pragma unroll
    for (int i = 0; i < 32; ++i) wr[i] = active ? (one_m * w3[co * 32 + i]) : 0.0f;

    const uint8_t* sbase = s2t + (size_t)b * 32 * T_STEPS;
    const uint4* bmv = (const uint4*)(bm2 + (size_t)b * NB_BLK);
    float* ob = out + (size_t)b * T_STEPS * 10 + co;

    float v = 0.0f;
    for (int sb = 0; sb < 16; ++sb) {
        uint4 bm = bmv[sb];
        if ((bm.x | bm.y | bm.z | bm.w) == 0u) {
            if (v != 0.0f) {
                for (int blk = 0; blk < 16 && v != 0.0f; ++blk) {
#pragma unroll
                    for (int j = 0; j < 16; ++j) v *= alpha;
                }
            }
            continue;
        }
        for (int blk = 0; blk < 16; ++blk) {
            uint32_t d = (blk < 4) ? bm.x : (blk < 8) ? bm.y
                       : (blk < 12) ? bm.z : bm.w;
            uint32_t byte = (d >> ((blk & 3) * 8)) & 0xffu;
            if (byte == 0u) {
                if (v != 0.0f) {
#pragma unroll
                    for (int j = 0; j < 16; ++j) v *= alpha;
                }
                continue;
            }
            const int t0 = (sb * 16 + blk) * 16;
            uint4 S[32];
#pragma unroll
            for (int c = 0; c < 32; ++c)
                S[c] = *(const uint4*)(sbase + (size_t)c * T_STEPS + t0);
#pragma unroll
            for (int j = 0; j < 16; ++j) {
                float xv[32];
#pragma unroll
                for (int c = 0; c < 32; ++c) {
                    uint32_t dd = (j < 4) ? S[c].x : (j < 8) ? S[c].y
                                : (j < 12) ? S[c].z : S[c].w;
                    xv[c] = ubf(dd, j & 3);
                }
                float p0 = fmaf(wr[1], xv[1], wr[0] * xv[0]);
                p0 = fmaf(wr[2],  xv[2],  p0); p0 = fmaf(wr[3],  xv[3],  p0);
                p0 = fmaf(wr[4],  xv[4],  p0); p0 = fmaf(wr[5],  xv[5],  p0);
                p0 = fmaf(wr[6],  xv[6],  p0); p0 = fmaf(wr[7],  xv[7],  p0);
                float p1 = fmaf(wr[9], xv[9], wr[8] * xv[8]);
                p1 = fmaf(wr[10], xv[10], p1); p1 = fmaf(wr[11], xv[11], p1);
                p1 = fmaf(wr[12], xv[12], p1); p1 = fmaf(wr[13], xv[13], p1);
                p1 = fmaf(wr[14], xv[14], p1); p1 = fmaf(wr[15], xv[15], p1);
                float p2 = fmaf(wr[17], xv[17], wr[16] * xv[16]);
                p2 = fmaf(wr[18], xv[18], p2); p2 = fmaf(wr[19], xv[19], p2);
                p2 = fmaf(wr[20], xv[20], p2); p2 = fmaf(wr[21], xv[21], p2);
                p2 = fmaf(wr[22], xv[22], p2); p2 = fmaf(wr[23], xv[23], p2);
                float p3 = fmaf(wr[25], xv[25], wr[24] * xv[24]);
                p3 = fmaf(wr[26], xv[26], p3); p3 = fmaf(wr[27], xv[27], p3);
                p3 = fmaf(wr[28], xv[28], p3); p3 = fmaf(wr[29], xv[29], p3);
                p3 = fmaf(wr[30], xv[30], p3); p3 = fmaf(wr[31], xv[31], p3);
                float xs = (p0 + p1) + (p2 + p3);
                float s = lif_step(v, xs, alpha);
                if (active && s != 0.0f) ob[(size_t)(t0 + j) * 10] = s;
            }
        }
    }
}

extern "C" void kernel_launch(void* const* d_in, const int* in_sizes, int n_in,
                              void* d_out, int out_size, void* d_ws, size_t ws_size,
                              hipStream_t stream)
{
    const float* data = (const float*)d_in[0];
    const float* w1   = (const float*)d_in[1];
    const float* w2   = (const float*)d_in[2];
    const float* w3   = (const float*)d_in[3];
    float* out = (float*)d_out;

    // ws layout (needs 48 MiB + 128 KiB):
    //   [0, 16M)    s1t  u8 [256][16][4096]
    //   [16M, 48M)  phase A: y chunk fp32 [128][16][4096]; later s2t u8 [256][32][4096]
    //   [48M, ..)   bm1 (64 KiB), bm2 (64 KiB)
    uint8_t* ws  = (uint8_t*)d_ws;
    uint8_t* s1t = ws;
    float*   ybf = (float*)(ws + (16u << 20));
    uint8_t* s2t = ws + (16u << 20);
    uint8_t* bm1 = ws + (48u << 20);
    uint8_t* bm2 = bm1 + (64u << 10);

    const float alpha = expf(-1.0f / 20.0f);
    const float one_m = 1.0f - alpha;

    kzero<<<2048, 256, 0, stream>>>((float4*)d_out, (float4*)bm1,
                                    (BATCH * T_STEPS * 10 * 4) / 16,
                                    (128 * 1024) / 16);
    for (int c = 0; c < 2; ++c) {
        int b0 = c * CHUNK_B;
        gemm1<<<CHUNK_B * 64, 256, 0, stream>>>(data, w1, ybf, one_m, b0);
        scan1<<<CHUNK_B / 4, 64, 0, stream>>>(ybf, s1t, bm1, alpha, b0);
    }
    scan2<<<BATCH / 2, 64, 0, stream>>>(s1t, w2, s2t, bm1, bm2, alpha, one_m);
    scan3<<<BATCH / 4, 64, 0, stream>>>(s2t, w3, out, bm2, alpha, one_m);
}